// Round 1
// 105.383 us; speedup vs baseline: 1.0616x; 1.0616x over previous
//
#include <hip/hip_runtime.h>
#include <hip/hip_bf16.h>
#include <math.h>

// Problem constants
#define BB 64
#define QQ 100
#define NN 16
#define CC 2048            // NUM_CLASSES + 1
#define TIME_WEIGHT 2.0f
#define EOS_COEF 0.1f

__device__ __forceinline__ double readlane_d(double x, int lane) {
    int lo = __builtin_amdgcn_readlane(__double2loint(x), lane);
    int hi = __builtin_amdgcn_readlane(__double2hiint(x), lane);
    return __hiloint2double(hi, lo);
}

// fmin with a DPP-permuted copy of x (both 32-bit halves moved coherently).
// old = src + bound_ctrl:0 => invalid/masked source lanes keep their own
// value, which is a no-op for fmin. All uses here are rotations/permutes
// within a 16-lane row under full exec, so every source lane is valid anyway.
template <int CTRL>
__device__ __forceinline__ double dpp_fmin_f64(double x) {
    int lo_s = __double2loint(x), hi_s = __double2hiint(x);
    int lo = __builtin_amdgcn_update_dpp(lo_s, lo_s, CTRL, 0xF, 0xF, false);
    int hi = __builtin_amdgcn_update_dpp(hi_s, hi_s, CTRL, 0xF, 0xF, false);
    return fmin(x, __hiloint2double(hi, lo));
}

// ---------------------------------------------------------------------------
// Kernel 1: per (b,q) row (one wave each):
//   logZ[b,q] = logsumexp(logits[b,q,:])
//   Cg[b][n][q] = -softmax[label_n] + 2*|pt - ts_n|   (transposed cost matrix)
//   lsepart[block] = sum over 4 rows of (logZ - logit[class 0])   [EOS nll]
// Block 0 additionally zero-inits the atomic accumulators for kernel 2.
// ---------------------------------------------------------------------------
__global__ __launch_bounds__(256) void lse_cost_kernel(
    const float* __restrict__ logits, const float* __restrict__ ptime,
    const int* __restrict__ labels, const float* __restrict__ tstamp,
    float* __restrict__ logZ, float* __restrict__ Cg,
    float* __restrict__ lsepart, float* __restrict__ sums, int* __restrict__ counter)
{
    if (blockIdx.x == 0 && threadIdx.x == 0) {
        sums[0] = 0.f; sums[1] = 0.f; *counter = 0;
    }
    const int wave = threadIdx.x >> 6;
    const int lane = threadIdx.x & 63;
    const int bq = blockIdx.x * 4 + wave;          // < 6400
    const int b = bq / QQ, q = bq % QQ;
    const float4* row4 = (const float4*)(logits + (size_t)bq * CC);

    float4 v[8];
    #pragma unroll
    for (int c = 0; c < 8; ++c) v[c] = row4[c * 64 + lane];

    float m = -INFINITY;
    #pragma unroll
    for (int c = 0; c < 8; ++c)
        m = fmaxf(m, fmaxf(fmaxf(v[c].x, v[c].y), fmaxf(v[c].z, v[c].w)));
    #pragma unroll
    for (int s = 1; s < 64; s <<= 1) m = fmaxf(m, __shfl_xor(m, s, 64));

    float sum = 0.f;
    #pragma unroll
    for (int c = 0; c < 8; ++c)
        sum += expf(v[c].x - m) + expf(v[c].y - m) +
               expf(v[c].z - m) + expf(v[c].w - m);
    #pragma unroll
    for (int s = 1; s < 64; s <<= 1) sum += __shfl_xor(sum, s, 64);

    const float lz = m + logf(sum);
    if (lane == 0) logZ[bq] = lz;

    // cost-matrix entries (lanes 0..15: one target each)
    const float pt = ptime[bq];
    if (lane < NN) {
        int lab = labels[b * NN + lane];
        float lg = logits[(size_t)bq * CC + lab];     // L1-hot gather (same row)
        float cc = -expf(lg - lz);
        float ct = fabsf(pt - tstamp[b * NN + lane]);
        float val = cc + TIME_WEIGHT * ct;
        if (isnan(val)) val = 100.0f;
        else if (isinf(val)) val = (val > 0.f) ? 100.0f : -100.0f;
        Cg[((size_t)b * NN + lane) * QQ + q] = val;
    }

    // EOS nll partial: nll0 = logZ - logit[class 0]
    __shared__ float red[4];
    if (lane == 0) red[wave] = lz - logits[(size_t)bq * CC];
    __syncthreads();
    if (threadIdx.x == 0)
        lsepart[blockIdx.x] = red[0] + red[1] + red[2] + red[3];
}

// ---------------------------------------------------------------------------
// Kernel 2: Jonker-Volgenant assignment, one wave per batch.
// v2 changes (latency-bound kernel, 1 wave/CU, every stall fully exposed):
//  * cost matrix lives in LDS (6.4 KB, conflict-free lane-contiguous reads);
//    the old 16-way register switch had been demoted to SCRATCH by the
//    compiler (VGPR_Count=28 proved it) -> private-memory load per iteration.
//  * min-reduction over the 16-lane rows via DPP (quad_perm xor1/xor2 +
//    row_ror:4/8 + v_min_f64) instead of __shfl_xor's ds_swizzle pairs --
//    removes 4 lgkmcnt-latency stages from the per-iteration critical path.
//    Reduced value is bit-identical (min is order-independent, exact member
//    of the set), so the equality-ballot lowest-index tie-break (== np.argmin)
//    and the resulting assignment are unchanged.
// All double arithmetic remains operation-identical to the numpy _lsa.
// Fused tail: CE correction + L1 time partials -> device atomics; last of
// the 64 blocks folds lsepart and writes the final scalar loss.
// ---------------------------------------------------------------------------
__global__ __launch_bounds__(64) void hungarian_kernel(
    const float* __restrict__ Cg, const float* __restrict__ logits,
    const float* __restrict__ ptime, const int* __restrict__ labels,
    const float* __restrict__ tstamp, const float* __restrict__ logZ,
    const float* __restrict__ lsepart, float* __restrict__ sums,
    int* __restrict__ counter, float* __restrict__ out)
{
    const int b = blockIdx.x;
    const int t = threadIdx.x;

    __shared__ float costS[NN * QQ];   // [row][col], row stride 100 floats
    __shared__ int qsl[NN];

    // coalesced LDS fill: 25 x 256B loads
    const float* cgb = Cg + (size_t)b * NN * QQ;
    #pragma unroll
    for (int k = 0; k < 25; ++k) costS[k * 64 + t] = cgb[k * 64 + t];
    __syncthreads();

    // Lane t owns columns jc0 = t+1 and (if <=100) jc1 = t+65 (1-based).
    const int jc0 = t + 1;
    const int jc1 = t + 65;
    const bool has2 = (jc1 <= QQ);
    const int t2 = has2 ? (t + 64) : t;            // clamp keeps reads in-bounds

    double v0 = 0.0, v1 = 0.0;          // column potentials (owned)
    double ureg = 0.0;                  // lane r holds u[r+1] (lanes 0..15)
    int preg0 = 0, preg1 = 0;           // p[jc0], p[jc1] (0 = free)
    const double INF = __builtin_inf();

    for (int i = 1; i <= NN; ++i) {
        double minv0 = INF, minv1 = INF;
        bool used0 = false, used1 = false;
        int way0 = 0, way1 = 0;
        bool inTree = (t == i - 1);     // p[0] = i enters the tree at start
        int j0 = 0;
        int i0 = i;                      // p[0]

        while (true) {
            used0 |= (j0 == jc0);
            used1 |= (j0 == jc1);
            inTree = inTree || (t == i0 - 1);
            const double u_i0 = readlane_d(ureg, i0 - 1);

            // wave-uniform row: one conflict-free LDS read per owned column
            const int rowbase = (i0 - 1) * QQ;
            const double ca = (double)costS[rowbase + t];
            const double cb = (double)costS[rowbase + t2];

            if (!used0) {
                double cur = ca - u_i0 - v0;
                if (cur < minv0) { minv0 = cur; way0 = j0; }
            }
            if (has2 && !used1) {
                double cur = cb - u_i0 - v1;
                if (cur < minv1) { minv1 = cur; way1 = j0; }
            }

            // value-only min reduction, all-DPP within 16-lane rows:
            // quad xor1, quad xor2, row_ror:4, row_ror:8 -> row min in every
            // lane; then 4 readlanes + 3 fmin across rows.
            double m0 = used0 ? INF : minv0;
            double m1 = (has2 && !used1) ? minv1 : INF;
            double gmin = fmin(m0, m1);
            gmin = dpp_fmin_f64<0xB1>(gmin);    // quad_perm [1,0,3,2]  (xor 1)
            gmin = dpp_fmin_f64<0x4E>(gmin);    // quad_perm [2,3,0,1]  (xor 2)
            gmin = dpp_fmin_f64<0x124>(gmin);   // row_ror:4
            gmin = dpp_fmin_f64<0x128>(gmin);   // row_ror:8
            {
                double h0 = readlane_d(gmin, 0);
                double h1 = readlane_d(gmin, 16);
                double h2 = readlane_d(gmin, 32);
                double h3 = readlane_d(gmin, 48);
                gmin = fmin(fmin(h0, h1), fmin(h2, h3));
            }
            // winning column: ballot A (cols 1..64) has priority, then B
            unsigned long long A  = __ballot(!used0 && (minv0 == gmin));
            unsigned long long Bm = __ballot(has2 && !used1 && (minv1 == gmin));
            int j1 = (A != 0ull) ? ((int)__builtin_ctzll(A) + 1)
                                 : ((int)__builtin_ctzll(Bm) + 65);
            const double delta = gmin;

            if (inTree) ureg += delta;                   // u[p[used]] += delta
            if (used0) v0 -= delta; else minv0 -= delta;
            if (has2) { if (used1) v1 -= delta; else minv1 -= delta; }

            j0 = j1;
            int pj = (j0 <= 64) ? __builtin_amdgcn_readlane(preg0, j0 - 1)
                                : __builtin_amdgcn_readlane(preg1, j0 - 65);
            if (pj == 0) break;
            i0 = pj;
        }

        // augment along the alternating path (uniform walk)
        while (j0 != 0) {
            int jn = (j0 <= 64) ? __builtin_amdgcn_readlane(way0, j0 - 1)
                                : __builtin_amdgcn_readlane(way1, j0 - 65);
            int pv;
            if (jn == 0) pv = i;
            else pv = (jn <= 64) ? __builtin_amdgcn_readlane(preg0, jn - 1)
                                 : __builtin_amdgcn_readlane(preg1, jn - 65);
            if (j0 == jc0) preg0 = pv;
            if (has2 && j0 == jc1) preg1 = pv;
            j0 = jn;
        }
    }

    // extract matches: qsl[target row] = column
    if (preg0 > 0) qsl[preg0 - 1] = jc0 - 1;
    if (has2 && preg1 > 0) qsl[preg1 - 1] = jc1 - 1;
    __syncthreads();

    // fused tail: CE correction + time-loss partials for this batch
    float corr = 0.f, tl = 0.f;
    if (t < NN) {
        int qcol = qsl[t];
        int lab = labels[b * NN + t];
        int bq = b * QQ + qcol;
        float lz = logZ[bq];
        float lgm = logits[(size_t)bq * CC + lab];
        float lg0 = logits[(size_t)bq * CC];
        corr = (lz - lgm) - EOS_COEF * (lz - lg0);
        tl = fabsf(ptime[bq] - tstamp[b * NN + t]);
    }
    #pragma unroll
    for (int s = 1; s < 64; s <<= 1) {
        corr += __shfl_xor(corr, s, 64);
        tl   += __shfl_xor(tl, s, 64);
    }

    int old = 0;
    if (t == 0) {
        atomicAdd(&sums[0], corr);
        atomicAdd(&sums[1], tl);
        __threadfence();                 // release partials before counter bump
        old = atomicAdd(counter, 1);
    }
    old = __shfl(old, 0, 64);
    if (old == BB - 1) {                 // last block finalizes
        __threadfence();                 // acquire others' partials
        float r0 = 0.f;
        #pragma unroll
        for (int k = 0; k < 25; ++k) r0 += lsepart[t + 64 * k];   // 1600 = 64*25
        #pragma unroll
        for (int s = 1; s < 64; s <<= 1) r0 += __shfl_xor(r0, s, 64);
        if (t == 0) {
            float s0 = atomicAdd(&sums[0], 0.0f);
            float s1 = atomicAdd(&sums[1], 0.0f);
            const float sum_w = (float)(BB * NN) * 1.0f
                              + (float)(BB * (QQ - NN)) * EOS_COEF;   // 1561.6
            float loss_ce = (EOS_COEF * r0 + s0) / sum_w;
            float loss_t  = s1 / (float)(BB * NN);
            out[0] = loss_ce + TIME_WEIGHT * loss_t;
        }
    }
}

// ---------------------------------------------------------------------------
// Workspace layout (bytes):
//   [0,      25600)  : float logZ[6400]
//   [25600, 435200)  : float Cg[64*16*100]
//   [435200, 441600) : float lsepart[1600]
//   [441600, 441608) : float sums[2]   {ce_corr, time}   (zeroed by kernel 1)
//   [441608, 441612) : int   counter                     (zeroed by kernel 1)
// ---------------------------------------------------------------------------
extern "C" void kernel_launch(void* const* d_in, const int* in_sizes, int n_in,
                              void* d_out, int out_size, void* d_ws, size_t ws_size,
                              hipStream_t stream) {
    const float* logits = (const float*)d_in[0];   // [B,Q,2048]
    const float* ptime  = (const float*)d_in[1];   // [B,Q,1]
    const int*   labels = (const int*)d_in[2];     // [B,N]
    const float* tstamp = (const float*)d_in[3];   // [B,N,1]
    float* out = (float*)d_out;

    char* ws = (char*)d_ws;
    float* logZ    = (float*)ws;
    float* Cg      = (float*)(ws + 25600);
    float* lsepart = (float*)(ws + 435200);
    float* sums    = (float*)(ws + 441600);
    int*   counter = (int*)(ws + 441608);

    lse_cost_kernel<<<1600, 256, 0, stream>>>(logits, ptime, labels, tstamp,
                                              logZ, Cg, lsepart, sums, counter);
    hungarian_kernel<<<BB, 64, 0, stream>>>(Cg, logits, ptime, labels, tstamp,
                                            logZ, lsepart, sums, counter, out);
}